// Round 21
// baseline (350.251 us; speedup 1.0000x reference)
//
#include <hip/hip_runtime.h>
#include <hip/hip_bf16.h>

#define N_PTS   40000
#define N_B     2
#define N_P     128
#define N_K     32
#define N_KC    4
#define N_FEAT  128
#define NQ2     (N_B * N_P * N_K)   // 8192
#define BIGF    3.0e38f

#define K1SUB   8
#define K1RANGE (N_PTS / K1SUB)     // 5000
#define QCAP1   512                 // knn1 cap (E[n]=341)
#define LBUF1   320                 // knn1 per-block LDS buffer

#define QCAP    96                  // knn2 per-query cap (E[n]=42)

#define TAU2    4.0e-3f             // (2.2*r4)^2 ; tau=0.0632
#define TAU1    1.6e-2f             // (2.2*r32)^2

#define NG      15                  // grid cells per dim; h=1/15 > tau2
#define NCELL   (NG * NG * NG)      // 3375
#define GB_BLK  20                  // grid-build blocks per batch
#define GB_PER  (N_PTS / GB_BLK)    // 2000 pts per block

#define NLOSSB  2048                // loss blocks (4 waves each = 8192 queries)

// Globals (zero-init at load; consumers reset their own counters each call).
__device__ int    g_sidx[N_P];
__device__ int    g_fidx[NQ2];
__device__ int    g_q1cnt[256];
__device__ unsigned long long g_q1list[256 * QCAP1];   // 1 MB
__device__ int    g_qcnt[NQ2 * 16];                    // padded counters
__device__ float2 g_qlist[(size_t)NQ2 * QCAP];         // 6.3 MB
__device__ int    g_bincnt[N_B * NCELL];               // histogram (reset by scan)
__device__ int    g_binstart[N_B * (NCELL + 1)];
__device__ int    g_cursor[N_B * NCELL];               // scatter cursors
__device__ float4 g_cpts[N_B * N_PTS];                 // bin-sorted clean pts (x,y,z,pp)
__device__ int    g_cpidx[N_B * N_PTS];                // original indices
__device__ float  g_lploss[NLOSSB];                    // per-block partials (plain stores)
__device__ float  g_M3[9];
__device__ float  g_WxS[9];

__device__ __forceinline__ int clampi(int v, int lo, int hi) { return v < lo ? lo : (v > hi ? hi : v); }

__device__ __forceinline__ unsigned long long packkey(float d, int idx)
{
    unsigned int u = __float_as_uint(d);
    u ^= (u >> 31) ? 0xFFFFFFFFu : 0x80000000u;
    return ((unsigned long long)u << 32) | (unsigned int)idx;
}

__device__ __forceinline__ int cell_of(float x, float y, float z)
{
    const int cx = clampi((int)(x * NG), 0, NG - 1);
    const int cy = clampi((int)(y * NG), 0, NG - 1);
    const int cz = clampi((int)(z * NG), 0, NG - 1);
    return cx + NG * (cy + NG * cz);
}

// ---------------------------------------------------------------------------
// Grid build 1/3 (R20 verbatim): per-block LDS histogram, no-return merge.
// ---------------------------------------------------------------------------
__global__ __launch_bounds__(256) void grid_hist_kernel(
    const float* __restrict__ clean)
{
    __shared__ int hist[NCELL];     // 13.5 KB
    const int bb  = blockIdx.y;
    const int blk = blockIdx.x;
    const int tid = threadIdx.x;
    const float* cb = clean + bb * (N_PTS * 3);

    for (int i = tid; i < NCELL; i += 256) hist[i] = 0;
    __syncthreads();

    const int j0 = blk * GB_PER;
    for (int j = j0 + tid; j < j0 + GB_PER; j += 256) {
        const float x = cb[j * 3 + 0], y = cb[j * 3 + 1], z = cb[j * 3 + 2];
        atomicAdd(&hist[cell_of(x, y, z)], 1);
    }
    __syncthreads();

    for (int i = tid; i < NCELL; i += 256) {
        const int v = hist[i];
        if (v) atomicAdd(&g_bincnt[bb * NCELL + i], v);   // no-return: pipelines freely
    }
}

// ---------------------------------------------------------------------------
// Grid build 2/3: prefix scan + M3/Wx hoist (loss was recomputing M3 per
// block — 2048 serial 128-iter loops). bb==0 also writes g_M3/g_WxS.
// Consume-and-resets g_bincnt.
// ---------------------------------------------------------------------------
__global__ __launch_bounds__(256) void grid_scan_kernel(
    const float* __restrict__ Wf,
    const float* __restrict__ Wx,
    const float* __restrict__ Wc)
{
    __shared__ int wsum[4], woff[4];
    const int bb  = blockIdx.x;
    const int tid = threadIdx.x, lane = tid & 63, wv = tid >> 6;

    if (bb == 0 && tid < 9) {
        const int d = tid / 3, e = tid % 3;
        float acc = 0.0f;
        for (int f0 = 0; f0 < N_FEAT; ++f0)
            acc += Wf[d * N_FEAT + f0] * Wc[f0 * 3 + e];
        g_M3[tid]  = acc;
        g_WxS[tid] = Wx[tid];
    }

    int lvals[14];
    int lsum = 0;
#pragma unroll
    for (int t = 0; t < 14; ++t) {
        const int idx = tid * 14 + t;
        lvals[t] = (idx < NCELL) ? g_bincnt[bb * NCELL + idx] : 0;
        lsum += lvals[t];
    }
    int v = lsum;
#pragma unroll
    for (int off = 1; off < 64; off <<= 1) {
        const int n = __shfl_up(v, off);
        if (lane >= off) v += n;
    }
    if (lane == 63) wsum[wv] = v;
    __syncthreads();
    if (tid == 0) { int r = 0; for (int w = 0; w < 4; ++w) { woff[w] = r; r += wsum[w]; } }
    __syncthreads();

    int run = woff[wv] + (v - lsum);    // exclusive prefix for this thread's chunk
#pragma unroll
    for (int t = 0; t < 14; ++t) {
        const int idx = tid * 14 + t;
        if (idx < NCELL) {
            g_binstart[bb * (NCELL + 1) + idx] = run;
            g_cursor[bb * NCELL + idx] = run;
            g_bincnt[bb * NCELL + idx] = 0;    // reset for next call
            run += lvals[t];
        }
    }
    if (tid == 0) g_binstart[bb * (NCELL + 1) + NCELL] = N_PTS;
}

// ---------------------------------------------------------------------------
// Grid build 3/3 (R20 verbatim): scatter via low-contention cursor atomics.
// ---------------------------------------------------------------------------
__global__ __launch_bounds__(256) void grid_scatter_kernel(
    const float* __restrict__ clean)
{
    const int bb  = blockIdx.y;
    const int blk = blockIdx.x;
    const int tid = threadIdx.x;
    const float* cb = clean + bb * (N_PTS * 3);

    const int j0 = blk * GB_PER;
    for (int j = j0 + tid; j < j0 + GB_PER; j += 256) {
        const float x = cb[j * 3 + 0], y = cb[j * 3 + 1], z = cb[j * 3 + 2];
        const int c = cell_of(x, y, z);
        const int pos = atomicAdd(&g_cursor[bb * NCELL + c], 1);
        const float pp = fmaf(z, z, fmaf(y, y, x * x));
        g_cpts[bb * N_PTS + pos]  = make_float4(x, y, z, pp);
        g_cpidx[bb * N_PTS + pos] = j;
    }
}

// ---------------------------------------------------------------------------
// sidx decode (proven, inlined per block).
// ---------------------------------------------------------------------------
__device__ __forceinline__ int decode_sidx(const void* sidx_raw, int p, int tid,
                                           int* flags, int* si_s)
{
    if (tid == 0) { flags[0] = 1; flags[1] = 1; flags[2] = 1; flags[3] = 1; }
    __syncthreads();
    const int*       p32 = (const int*)sidx_raw;
    const long long* p64 = (const long long*)sidx_raw;
    const float*     pf  = (const float*)sidx_raw;
    if (tid < 128) {
        const int       v32 = p32[tid];
        const long long v64 = p64[tid];
        const float     vf  = pf[tid];
        if (!(v32 >= 0 && v32 < N_PTS)) atomicAnd(&flags[0], 0);
        if ((tid & 1) && v32 != 0)      atomicAnd(&flags[1], 0);
        if (!(v64 >= 0 && v64 < N_PTS)) atomicAnd(&flags[2], 0);
        if (!(vf >= 0.0f && vf < (float)N_PTS && vf == floorf(vf))) atomicAnd(&flags[3], 0);
    }
    __syncthreads();
    if (tid == 0) {
        int si;
        if (flags[0] && !(flags[1] && flags[2])) si = p32[p];
        else if (flags[2])                       si = (int)p64[p];
        else if (flags[3])                       si = (int)(pf[p] + 0.5f);
        else                                     si = 0;
        *si_s = clampi(si, 0, N_PTS - 1);
    }
    __syncthreads();
    return *si_s;
}

// ---------------------------------------------------------------------------
// KNN1 scan (verbatim): LDS-buffered tau-append.
// ---------------------------------------------------------------------------
__global__ __launch_bounds__(256) void knn1_scan_kernel(
    const float* __restrict__ noisy,
    const void* __restrict__ sidx_raw)
{
    __shared__ unsigned long long buf[LBUF1];
    __shared__ int flags[4];
    __shared__ int si_s;
    __shared__ int lcnt;
    __shared__ int base_s;
    const int qb  = blockIdx.x;
    const int sub = blockIdx.y;
    const int b   = qb >> 7;
    const int p   = qb & 127;
    const int tid = threadIdx.x;
    const float* nb = noisy + b * (N_PTS * 3);

    const int si = decode_sidx(sidx_raw, p, tid, flags, &si_s);
    if (sub == 0 && tid == 0) g_sidx[p] = si;
    if (tid == 0) lcnt = 0;
    const float qx = nb[si * 3 + 0];
    const float qy = nb[si * 3 + 1];
    const float qz = nb[si * 3 + 2];
    __syncthreads();

    const int jbeg = sub * K1RANGE;
    const int jend = jbeg + K1RANGE;
    for (int j = jbeg + tid; j < jend; j += 256) {
        const float dx = qx - nb[j * 3 + 0];
        const float dy = qy - nb[j * 3 + 1];
        const float dz = qz - nb[j * 3 + 2];
        const float d2 = fmaf(dz, dz, fmaf(dy, dy, dx * dx));
        if (d2 < TAU1) {
            const int slot = atomicAdd(&lcnt, 1);
            if (slot < LBUF1)
                buf[slot] = ((unsigned long long)__float_as_uint(d2) << 32) | (unsigned int)j;
        }
    }
    __syncthreads();

    const int cnt = lcnt;
    if (tid == 0) {
        const int add = (cnt <= LBUF1) ? cnt : (QCAP1 + 1000);
        base_s = atomicAdd(&g_q1cnt[qb], add);
    }
    __syncthreads();

    const int base = base_s;
    const int n = (cnt < LBUF1) ? cnt : LBUF1;
    for (int i = tid; i < n; i += 256) {
        const int o = base + i;
        if (o < QCAP1) g_q1list[qb * QCAP1 + o] = buf[i];
    }
}

// ---------------------------------------------------------------------------
// KNN1 merge (verbatim): 512-key bitonic; inline exact fallback.
// ---------------------------------------------------------------------------
__global__ __launch_bounds__(256) void knn1_merge_kernel(
    const float* __restrict__ noisy)
{
    __shared__ unsigned long long keys[2048];
    const int qb  = blockIdx.x;
    const int tid = threadIdx.x;
    const int cnt = g_q1cnt[qb];

    if (cnt >= 32 && cnt <= QCAP1) {
        for (int i = tid; i < QCAP1; i += 256)
            keys[i] = (i < cnt) ? g_q1list[qb * QCAP1 + i] : ~0ULL;
        __syncthreads();
        for (int k = 2; k <= QCAP1; k <<= 1) {
            for (int jj = k >> 1; jj > 0; jj >>= 1) {
                const int idx = tid;
                const int i = ((idx & ~(jj - 1)) << 1) | (idx & (jj - 1));
                const int partner = i | jj;
                const bool asc = ((i & k) == 0);
                const unsigned long long a = keys[i];
                const unsigned long long c = keys[partner];
                if ((a > c) == asc) { keys[i] = c; keys[partner] = a; }
                __syncthreads();
            }
        }
    } else {
        const int b = qb >> 7;
        const float* nb = noisy + b * (N_PTS * 3);
        const int si = g_sidx[qb & 127];
        const float qx = nb[si * 3 + 0];
        const float qy = nb[si * 3 + 1];
        const float qz = nb[si * 3 + 2];

        float bd[8]; int bi[8];
#pragma unroll
        for (int i = 0; i < 8; ++i) { bd[i] = BIGF; bi[i] = 0x7fffffff; }
        for (int j = tid; j < N_PTS; j += 256) {
            const float dx = qx - nb[j * 3 + 0];
            const float dy = qy - nb[j * 3 + 1];
            const float dz = qz - nb[j * 3 + 2];
            const float d2 = fmaf(dz, dz, fmaf(dy, dy, dx * dx));
            if (d2 < bd[7]) {
                bd[7] = d2; bi[7] = j;
#pragma unroll
                for (int t = 7; t > 0; --t) {
                    if (bd[t] < bd[t - 1]) {
                        float td = bd[t]; bd[t] = bd[t - 1]; bd[t - 1] = td;
                        int   ti = bi[t]; bi[t] = bi[t - 1]; bi[t - 1] = ti;
                    }
                }
            }
        }
#pragma unroll
        for (int t = 0; t < 8; ++t)
            keys[tid * 8 + t] = ((unsigned long long)__float_as_uint(bd[t]) << 32)
                              | (unsigned int)bi[t];
        __syncthreads();
        for (int k = 2; k <= 2048; k <<= 1) {
            for (int jj = k >> 1; jj > 0; jj >>= 1) {
#pragma unroll
                for (int base = 0; base < 2048; base += 256) {
                    const int i = base + tid;
                    const int partner = i ^ jj;
                    if (partner > i) {
                        const bool asc = ((i & k) == 0);
                        const unsigned long long a = keys[i];
                        const unsigned long long c = keys[partner];
                        if ((a > c) == asc) { keys[i] = c; keys[partner] = a; }
                    }
                }
                __syncthreads();
            }
        }
    }

    if (tid < 32) {
        const int idx = (int)(keys[tid] & 0xFFFFFFFFull);
        g_fidx[qb * 32 + tid] = clampi(idx, 0, N_PTS - 1);
    }
    if (tid == 0) g_q1cnt[qb] = 0;
}

// ---------------------------------------------------------------------------
// KNN2 via spatial grid (verbatim): wave per query, 27-cell walk.
// ---------------------------------------------------------------------------
__global__ __launch_bounds__(256) void knn2_grid_kernel(
    const float* __restrict__ noisy)
{
    __shared__ float2 buf[4][QCAP];    // 3 KB
    __shared__ int    bcnt[4];
    const int tid  = threadIdx.x;
    const int wv   = tid >> 6;
    const int lane = tid & 63;
    const int g    = blockIdx.x * 4 + wv;
    const int b    = g >> 12;
    const float* nb = noisy + b * (N_PTS * 3);

    if (lane == 0) bcnt[wv] = 0;

    const int fid = clampi(g_fidx[g], 0, N_PTS - 1);
    const float fx = nb[fid * 3 + 0];
    const float fy = nb[fid * 3 + 1];
    const float fz = nb[fid * 3 + 2];
    const float fm2x = -2.0f * fx, fm2y = -2.0f * fy, fm2z = -2.0f * fz;
    const float ff = fmaf(fz, fz, fmaf(fy, fy, fx * fx));
    const float taup = TAU2 - ff;

    const int cfx = clampi((int)(fx * NG), 0, NG - 1);
    const int cfy = clampi((int)(fy * NG), 0, NG - 1);
    const int cfz = clampi((int)(fz * NG), 0, NG - 1);
    const int bso = b * (NCELL + 1);
    const int bpo = b * N_PTS;

    if (lane < 27) {
        const int cx = cfx + (lane % 3) - 1;
        const int cy = cfy + ((lane / 3) % 3) - 1;
        const int cz = cfz + (lane / 9) - 1;
        if (cx >= 0 && cx < NG && cy >= 0 && cy < NG && cz >= 0 && cz < NG) {
            const int c = cx + NG * (cy + NG * cz);
            const int s = g_binstart[bso + c];
            const int e = g_binstart[bso + c + 1];
            for (int k = s; k < e; ++k) {
                const float4 p = g_cpts[bpo + k];
                const float d2 = fmaf(fm2x, p.x, fmaf(fm2y, p.y, fmaf(fm2z, p.z, p.w)));
                if (d2 < taup) {
                    const int slot = atomicAdd(&bcnt[wv], 1);
                    if (slot < QCAP)
                        buf[wv][slot] = make_float2(d2, __int_as_float(g_cpidx[bpo + k]));
                }
            }
        }
    }
    __syncthreads();

    const int cnt = bcnt[wv];
    const int n = (cnt < QCAP) ? cnt : QCAP;
    for (int i = lane; i < n; i += 64)
        g_qlist[(size_t)g * QCAP + i] = buf[wv][i];
    if (lane == 0) g_qcnt[g * 16] = cnt;   // single producer: plain store
}

// ---------------------------------------------------------------------------
// Loss v3: wave-per-query butterfly top-4 + inline exact fallback.
// R20's ticket reduction (2048 same-address returning atomics + threadfence
// = ~50us serialization) replaced by a plain per-block slot store + a tiny
// final kernel. M3/Wx read from globals (hoisted to grid_scan).
// ---------------------------------------------------------------------------
__global__ __launch_bounds__(256) void loss_kernel(
    const float* __restrict__ noisy,
    const float* __restrict__ clean)
{
    __shared__ float red[4];
    const int tid  = threadIdx.x;
    const int wv   = tid >> 6;
    const int lane = tid & 63;
    const int g    = blockIdx.x * 4 + wv;
    const int b    = g >> 12;
    const int p    = (g >> 5) & 127;
    const float* nb = noisy + b * (N_PTS * 3);
    const float* cb = clean + b * (N_PTS * 3);

    const int cnt = g_qcnt[g * 16];
    const int fid = clampi(g_fidx[g], 0, N_PTS - 1);
    const float fx = nb[fid * 3 + 0], fy = nb[fid * 3 + 1], fz = nb[fid * 3 + 2];
    int nn[4];

    if (cnt >= 4 && cnt <= QCAP) {
        const float2* lst = g_qlist + (size_t)g * QCAP;
        unsigned long long e0 = ~0ULL, e1 = ~0ULL;
        if (lane < cnt) {
            const float2 a = lst[lane];
            e0 = packkey(a.x, __float_as_int(a.y));
        }
        if (lane + 64 < cnt) {
            const float2 a = lst[lane + 64];
            e1 = packkey(a.x, __float_as_int(a.y));
        }
        if (e1 < e0) { unsigned long long t = e0; e0 = e1; e1 = t; }

        int c = 0;
#pragma unroll
        for (int r = 0; r < 4; ++r) {
            const unsigned long long h = (c == 0) ? e0 : ((c == 1) ? e1 : ~0ULL);
            unsigned long long m = h;
#pragma unroll
            for (int off = 32; off; off >>= 1) {
                const unsigned long long o = __shfl_xor(m, off);
                if (o < m) m = o;
            }
            if (h == m) c++;
            nn[r] = (int)(m & 0xFFFFFFFFull);
        }
    } else {
        float bd[4]; int bi[4];
#pragma unroll
        for (int t = 0; t < 4; ++t) { bd[t] = BIGF; bi[t] = 0x7fffffff; }
        for (int j = lane; j < N_PTS; j += 64) {
            const float dx = fx - cb[j * 3 + 0];
            const float dy = fy - cb[j * 3 + 1];
            const float dz = fz - cb[j * 3 + 2];
            const float d2 = fmaf(dz, dz, fmaf(dy, dy, dx * dx));
            if (d2 < bd[3]) {
                bd[3] = d2; bi[3] = j;
#pragma unroll
                for (int t = 3; t > 0; --t) {
                    if (bd[t] < bd[t - 1]) {
                        float td = bd[t]; bd[t] = bd[t - 1]; bd[t - 1] = td;
                        int   ti = bi[t]; bi[t] = bi[t - 1]; bi[t - 1] = ti;
                    }
                }
            }
        }
        int cur = 0;
        for (int r = 0; r < 4; ++r) {
            float v  = (cur < 4) ? bd[cur] : BIGF;
            int   vi = (cur < 4) ? bi[cur] : 0x7fffffff;
            int   who = lane;
#pragma unroll
            for (int off = 32; off; off >>= 1) {
                const float v2  = __shfl_down(v, off);
                const int   vi2 = __shfl_down(vi, off);
                const int   w2  = __shfl_down(who, off);
                if (v2 < v || (v2 == v && vi2 < vi)) { v = v2; vi = vi2; who = w2; }
            }
            const int bvi = __shfl(vi, 0);
            const int bwh = __shfl(who, 0);
            nn[r] = bvi;
            if (lane == bwh) cur++;
        }
    }

    float t2 = 0.0f;
    if (lane == 0) {
        const int si = g_sidx[p];
        const float qx = nb[si * 3 + 0], qy = nb[si * 3 + 1], qz = nb[si * 3 + 2];
        const int n0 = clampi(nn[0], 0, N_PTS - 1), n1 = clampi(nn[1], 0, N_PTS - 1);
        const int n2 = clampi(nn[2], 0, N_PTS - 1), n3 = clampi(nn[3], 0, N_PTS - 1);
        const float mx = 0.25f * (cb[n0*3+0] + cb[n1*3+0] + cb[n2*3+0] + cb[n3*3+0]);
        const float my = 0.25f * (cb[n0*3+1] + cb[n1*3+1] + cb[n2*3+1] + cb[n3*3+1]);
        const float mz = 0.25f * (cb[n0*3+2] + cb[n1*3+2] + cb[n2*3+2] + cb[n3*3+2]);

        const float gx = mx - fx, gy = my - fy, gz = mz - fz;
        const float rx = fx - qx, ry = fy - qy, rz = fz - qz;
        const float ex = rx * g_WxS[0] + ry * g_WxS[3] + rz * g_WxS[6] + qx * g_M3[0] + qy * g_M3[3] + qz * g_M3[6];
        const float ey = rx * g_WxS[1] + ry * g_WxS[4] + rz * g_WxS[7] + qx * g_M3[1] + qy * g_M3[4] + qz * g_M3[7];
        const float ez = rx * g_WxS[2] + ry * g_WxS[5] + rz * g_WxS[8] + qx * g_M3[2] + qy * g_M3[5] + qz * g_M3[8];
        const float dx = ex - gx, dy = ey - gy, dz = ez - gz;
        t2 = dx * dx + dy * dy + dz * dz;
        g_qcnt[g * 16] = 0;
    }

    if (lane == 0) red[wv] = t2;
    __syncthreads();
    if (tid == 0) g_lploss[blockIdx.x] = (red[0] + red[1]) + (red[2] + red[3]);
}

// ---------------------------------------------------------------------------
// Final: sum 2048 per-block partials (1 block, 256 thr).
// ---------------------------------------------------------------------------
__global__ __launch_bounds__(256) void final_kernel(float* __restrict__ out)
{
    __shared__ float red[4];
    const int tid = threadIdx.x;
    float v = 0.0f;
    for (int i = tid; i < NLOSSB; i += 256) v += g_lploss[i];
#pragma unroll
    for (int off = 32; off; off >>= 1) v += __shfl_down(v, off);
    if ((tid & 63) == 0) red[tid >> 6] = v;
    __syncthreads();
    if (tid == 0) out[0] = ((red[0] + red[1]) + (red[2] + red[3])) * (50.0f / 8192.0f);
}

extern "C" void kernel_launch(void* const* d_in, const int* in_sizes, int n_in,
                              void* d_out, int out_size, void* d_ws, size_t ws_size,
                              hipStream_t stream)
{
    (void)d_ws; (void)ws_size; (void)in_sizes; (void)n_in; (void)out_size;

    const float* noisy = (const float*)d_in[0];
    const float* clean = (const float*)d_in[1];
    const float* Wf    = (const float*)d_in[3];
    const float* Wx    = (const float*)d_in[4];
    const float* Wc    = (const float*)d_in[5];

    grid_hist_kernel<<<dim3(GB_BLK, N_B), 256, 0, stream>>>(clean);
    grid_scan_kernel<<<N_B, 256, 0, stream>>>(Wf, Wx, Wc);
    grid_scatter_kernel<<<dim3(GB_BLK, N_B), 256, 0, stream>>>(clean);
    knn1_scan_kernel<<<dim3(256, K1SUB), 256, 0, stream>>>(noisy, d_in[2]);
    knn1_merge_kernel<<<256, 256, 0, stream>>>(noisy);
    knn2_grid_kernel<<<NLOSSB, 256, 0, stream>>>(noisy);
    loss_kernel<<<NLOSSB, 256, 0, stream>>>(noisy, clean);
    final_kernel<<<1, 256, 0, stream>>>((float*)d_out);
}

// Round 22
// 131.168 us; speedup vs baseline: 2.6703x; 2.6703x over previous
//
#include <hip/hip_runtime.h>
#include <hip/hip_bf16.h>

#define N_PTS   40000
#define N_B     2
#define N_P     128
#define N_K     32
#define N_KC    4
#define N_FEAT  128
#define NQ2     (N_B * N_P * N_K)   // 8192
#define BIGF    3.0e38f

#define K1SUB   8
#define K1RANGE (N_PTS / K1SUB)     // 5000
#define QCAP1   512                 // knn1 cap (E[n]=341)
#define LBUF1   320                 // knn1 per-block LDS buffer

#define QCAP    96                  // knn2 per-query cap (E[n]=42)

#define TAU2    4.0e-3f             // (2.2*r4)^2 ; tau=0.0632
#define TAU1    1.6e-2f             // (2.2*r32)^2

#define NG      15                  // grid cells per dim; h=1/15 > tau2
#define NCELL   (NG * NG * NG)      // 3375
#define GB_BLK  20                  // grid-build blocks per batch
#define GB_PER  (N_PTS / GB_BLK)    // 2000 pts per block

#define NLOSSB  2048                // loss blocks (4 waves each = 8192 queries)

// Globals (zero-init at load; consumers reset their own counters each call).
__device__ int    g_sidx[N_P];
__device__ int    g_fidx[NQ2];
__device__ int    g_q1cnt[256];
__device__ unsigned long long g_q1list[256 * QCAP1];   // 1 MB
__device__ int    g_qcnt[NQ2 * 16];                    // padded counters
__device__ float2 g_qlist[(size_t)NQ2 * QCAP];         // 6.3 MB
__device__ int    g_bincnt[N_B * NCELL];               // histogram (reset by scan)
__device__ int    g_binstart[N_B * (NCELL + 1)];
__device__ int    g_cursor[N_B * NCELL];               // scatter cursors
__device__ float4 g_cpts[N_B * N_PTS];                 // bin-sorted clean pts (x,y,z,pp)
__device__ int    g_cpidx[N_B * N_PTS];                // original indices
__device__ float  g_lploss[NLOSSB];                    // per-block partials (plain stores)
__device__ float  g_M3[9];
__device__ float  g_WxS[9];

__device__ __forceinline__ int clampi(int v, int lo, int hi) { return v < lo ? lo : (v > hi ? hi : v); }

__device__ __forceinline__ unsigned long long packkey(float d, int idx)
{
    unsigned int u = __float_as_uint(d);
    u ^= (u >> 31) ? 0xFFFFFFFFu : 0x80000000u;
    return ((unsigned long long)u << 32) | (unsigned int)idx;
}

__device__ __forceinline__ int cell_of(float x, float y, float z)
{
    const int cx = clampi((int)(x * NG), 0, NG - 1);
    const int cy = clampi((int)(y * NG), 0, NG - 1);
    const int cz = clampi((int)(z * NG), 0, NG - 1);
    return cx + NG * (cy + NG * cz);
}

// ---------------------------------------------------------------------------
// Grid build 1/3 (verbatim): per-block LDS histogram, no-return merge.
// ---------------------------------------------------------------------------
__global__ __launch_bounds__(256) void grid_hist_kernel(
    const float* __restrict__ clean)
{
    __shared__ int hist[NCELL];     // 13.5 KB
    const int bb  = blockIdx.y;
    const int blk = blockIdx.x;
    const int tid = threadIdx.x;
    const float* cb = clean + bb * (N_PTS * 3);

    for (int i = tid; i < NCELL; i += 256) hist[i] = 0;
    __syncthreads();

    const int j0 = blk * GB_PER;
    for (int j = j0 + tid; j < j0 + GB_PER; j += 256) {
        const float x = cb[j * 3 + 0], y = cb[j * 3 + 1], z = cb[j * 3 + 2];
        atomicAdd(&hist[cell_of(x, y, z)], 1);
    }
    __syncthreads();

    for (int i = tid; i < NCELL; i += 256) {
        const int v = hist[i];
        if (v) atomicAdd(&g_bincnt[bb * NCELL + i], v);   // no-return: pipelines freely
    }
}

// ---------------------------------------------------------------------------
// Grid build 2/3: prefix scan + hoisted M3/Wx + hoisted sidx decode
// (knn1_scan's 2048 blocks were each redundantly re-voting the dtype).
// Consume-and-resets g_bincnt.
// ---------------------------------------------------------------------------
__global__ __launch_bounds__(256) void grid_scan_kernel(
    const void* __restrict__ sidx_raw,
    const float* __restrict__ Wf,
    const float* __restrict__ Wx,
    const float* __restrict__ Wc)
{
    __shared__ int wsum[4], woff[4];
    __shared__ int flags[4];
    const int bb  = blockIdx.x;
    const int tid = threadIdx.x, lane = tid & 63, wv = tid >> 6;

    if (bb == 0) {
        if (tid < 9) {
            const int d = tid / 3, e = tid % 3;
            float acc = 0.0f;
            for (int f0 = 0; f0 < N_FEAT; ++f0)
                acc += Wf[d * N_FEAT + f0] * Wc[f0 * 3 + e];
            g_M3[tid]  = acc;
            g_WxS[tid] = Wx[tid];
        }
        if (tid == 0) { flags[0] = 1; flags[1] = 1; flags[2] = 1; flags[3] = 1; }
        __syncthreads();
        const int*       p32 = (const int*)sidx_raw;
        const long long* p64 = (const long long*)sidx_raw;
        const float*     pf  = (const float*)sidx_raw;
        if (tid < 128) {
            const int       v32 = p32[tid];
            const long long v64 = p64[tid];
            const float     vf  = pf[tid];
            if (!(v32 >= 0 && v32 < N_PTS)) atomicAnd(&flags[0], 0);
            if ((tid & 1) && v32 != 0)      atomicAnd(&flags[1], 0);
            if (!(v64 >= 0 && v64 < N_PTS)) atomicAnd(&flags[2], 0);
            if (!(vf >= 0.0f && vf < (float)N_PTS && vf == floorf(vf))) atomicAnd(&flags[3], 0);
        }
        __syncthreads();
        if (tid < 128) {
            int si;
            if (flags[0] && !(flags[1] && flags[2])) si = p32[tid];
            else if (flags[2])                       si = (int)p64[tid];
            else if (flags[3])                       si = (int)(pf[tid] + 0.5f);
            else                                     si = 0;
            g_sidx[tid] = clampi(si, 0, N_PTS - 1);
        }
    }

    int lvals[14];
    int lsum = 0;
#pragma unroll
    for (int t = 0; t < 14; ++t) {
        const int idx = tid * 14 + t;
        lvals[t] = (idx < NCELL) ? g_bincnt[bb * NCELL + idx] : 0;
        lsum += lvals[t];
    }
    int v = lsum;
#pragma unroll
    for (int off = 1; off < 64; off <<= 1) {
        const int n = __shfl_up(v, off);
        if (lane >= off) v += n;
    }
    if (lane == 63) wsum[wv] = v;
    __syncthreads();
    if (tid == 0) { int r = 0; for (int w = 0; w < 4; ++w) { woff[w] = r; r += wsum[w]; } }
    __syncthreads();

    int run = woff[wv] + (v - lsum);    // exclusive prefix for this thread's chunk
#pragma unroll
    for (int t = 0; t < 14; ++t) {
        const int idx = tid * 14 + t;
        if (idx < NCELL) {
            g_binstart[bb * (NCELL + 1) + idx] = run;
            g_cursor[bb * NCELL + idx] = run;
            g_bincnt[bb * NCELL + idx] = 0;    // reset for next call
            run += lvals[t];
        }
    }
    if (tid == 0) g_binstart[bb * (NCELL + 1) + NCELL] = N_PTS;
}

// ---------------------------------------------------------------------------
// Grid build 3/3 (verbatim): scatter via low-contention cursor atomics.
// ---------------------------------------------------------------------------
__global__ __launch_bounds__(256) void grid_scatter_kernel(
    const float* __restrict__ clean)
{
    const int bb  = blockIdx.y;
    const int blk = blockIdx.x;
    const int tid = threadIdx.x;
    const float* cb = clean + bb * (N_PTS * 3);

    const int j0 = blk * GB_PER;
    for (int j = j0 + tid; j < j0 + GB_PER; j += 256) {
        const float x = cb[j * 3 + 0], y = cb[j * 3 + 1], z = cb[j * 3 + 2];
        const int c = cell_of(x, y, z);
        const int pos = atomicAdd(&g_cursor[bb * NCELL + c], 1);
        const float pp = fmaf(z, z, fmaf(y, y, x * x));
        g_cpts[bb * N_PTS + pos]  = make_float4(x, y, z, pp);
        g_cpidx[bb * N_PTS + pos] = j;
    }
}

// ---------------------------------------------------------------------------
// KNN1 scan: LDS-buffered tau-append; sidx read from g_sidx (decoded once
// in grid_scan, which runs earlier).
// ---------------------------------------------------------------------------
__global__ __launch_bounds__(256) void knn1_scan_kernel(
    const float* __restrict__ noisy)
{
    __shared__ unsigned long long buf[LBUF1];
    __shared__ int lcnt;
    __shared__ int base_s;
    const int qb  = blockIdx.x;
    const int sub = blockIdx.y;
    const int b   = qb >> 7;
    const int p   = qb & 127;
    const int tid = threadIdx.x;
    const float* nb = noisy + b * (N_PTS * 3);

    if (tid == 0) lcnt = 0;
    const int si = g_sidx[p];
    const float qx = nb[si * 3 + 0];
    const float qy = nb[si * 3 + 1];
    const float qz = nb[si * 3 + 2];
    __syncthreads();

    const int jbeg = sub * K1RANGE;
    const int jend = jbeg + K1RANGE;
    for (int j = jbeg + tid; j < jend; j += 256) {
        const float dx = qx - nb[j * 3 + 0];
        const float dy = qy - nb[j * 3 + 1];
        const float dz = qz - nb[j * 3 + 2];
        const float d2 = fmaf(dz, dz, fmaf(dy, dy, dx * dx));
        if (d2 < TAU1) {
            const int slot = atomicAdd(&lcnt, 1);
            if (slot < LBUF1)
                buf[slot] = ((unsigned long long)__float_as_uint(d2) << 32) | (unsigned int)j;
        }
    }
    __syncthreads();

    const int cnt = lcnt;
    if (tid == 0) {
        const int add = (cnt <= LBUF1) ? cnt : (QCAP1 + 1000);
        base_s = atomicAdd(&g_q1cnt[qb], add);
    }
    __syncthreads();

    const int base = base_s;
    const int n = (cnt < LBUF1) ? cnt : LBUF1;
    for (int i = tid; i < n; i += 256) {
        const int o = base + i;
        if (o < QCAP1) g_q1list[qb * QCAP1 + o] = buf[i];
    }
}

// ---------------------------------------------------------------------------
// KNN1 merge (verbatim): 512-key bitonic; inline exact fallback.
// ---------------------------------------------------------------------------
__global__ __launch_bounds__(256) void knn1_merge_kernel(
    const float* __restrict__ noisy)
{
    __shared__ unsigned long long keys[2048];
    const int qb  = blockIdx.x;
    const int tid = threadIdx.x;
    const int cnt = g_q1cnt[qb];

    if (cnt >= 32 && cnt <= QCAP1) {
        for (int i = tid; i < QCAP1; i += 256)
            keys[i] = (i < cnt) ? g_q1list[qb * QCAP1 + i] : ~0ULL;
        __syncthreads();
        for (int k = 2; k <= QCAP1; k <<= 1) {
            for (int jj = k >> 1; jj > 0; jj >>= 1) {
                const int idx = tid;
                const int i = ((idx & ~(jj - 1)) << 1) | (idx & (jj - 1));
                const int partner = i | jj;
                const bool asc = ((i & k) == 0);
                const unsigned long long a = keys[i];
                const unsigned long long c = keys[partner];
                if ((a > c) == asc) { keys[i] = c; keys[partner] = a; }
                __syncthreads();
            }
        }
    } else {
        const int b = qb >> 7;
        const float* nb = noisy + b * (N_PTS * 3);
        const int si = g_sidx[qb & 127];
        const float qx = nb[si * 3 + 0];
        const float qy = nb[si * 3 + 1];
        const float qz = nb[si * 3 + 2];

        float bd[8]; int bi[8];
#pragma unroll
        for (int i = 0; i < 8; ++i) { bd[i] = BIGF; bi[i] = 0x7fffffff; }
        for (int j = tid; j < N_PTS; j += 256) {
            const float dx = qx - nb[j * 3 + 0];
            const float dy = qy - nb[j * 3 + 1];
            const float dz = qz - nb[j * 3 + 2];
            const float d2 = fmaf(dz, dz, fmaf(dy, dy, dx * dx));
            if (d2 < bd[7]) {
                bd[7] = d2; bi[7] = j;
#pragma unroll
                for (int t = 7; t > 0; --t) {
                    if (bd[t] < bd[t - 1]) {
                        float td = bd[t]; bd[t] = bd[t - 1]; bd[t - 1] = td;
                        int   ti = bi[t]; bi[t] = bi[t - 1]; bi[t - 1] = ti;
                    }
                }
            }
        }
#pragma unroll
        for (int t = 0; t < 8; ++t)
            keys[tid * 8 + t] = ((unsigned long long)__float_as_uint(bd[t]) << 32)
                              | (unsigned int)bi[t];
        __syncthreads();
        for (int k = 2; k <= 2048; k <<= 1) {
            for (int jj = k >> 1; jj > 0; jj >>= 1) {
#pragma unroll
                for (int base = 0; base < 2048; base += 256) {
                    const int i = base + tid;
                    const int partner = i ^ jj;
                    if (partner > i) {
                        const bool asc = ((i & k) == 0);
                        const unsigned long long a = keys[i];
                        const unsigned long long c = keys[partner];
                        if ((a > c) == asc) { keys[i] = c; keys[partner] = a; }
                    }
                }
                __syncthreads();
            }
        }
    }

    if (tid < 32) {
        const int idx = (int)(keys[tid] & 0xFFFFFFFFull);
        g_fidx[qb * 32 + tid] = clampi(idx, 0, N_PTS - 1);
    }
    if (tid == 0) g_q1cnt[qb] = 0;
}

// ---------------------------------------------------------------------------
// KNN2 via spatial grid (verbatim): wave per query, 27-cell walk.
// ---------------------------------------------------------------------------
__global__ __launch_bounds__(256) void knn2_grid_kernel(
    const float* __restrict__ noisy)
{
    __shared__ float2 buf[4][QCAP];    // 3 KB
    __shared__ int    bcnt[4];
    const int tid  = threadIdx.x;
    const int wv   = tid >> 6;
    const int lane = tid & 63;
    const int g    = blockIdx.x * 4 + wv;
    const int b    = g >> 12;
    const float* nb = noisy + b * (N_PTS * 3);

    if (lane == 0) bcnt[wv] = 0;

    const int fid = clampi(g_fidx[g], 0, N_PTS - 1);
    const float fx = nb[fid * 3 + 0];
    const float fy = nb[fid * 3 + 1];
    const float fz = nb[fid * 3 + 2];
    const float fm2x = -2.0f * fx, fm2y = -2.0f * fy, fm2z = -2.0f * fz;
    const float ff = fmaf(fz, fz, fmaf(fy, fy, fx * fx));
    const float taup = TAU2 - ff;

    const int cfx = clampi((int)(fx * NG), 0, NG - 1);
    const int cfy = clampi((int)(fy * NG), 0, NG - 1);
    const int cfz = clampi((int)(fz * NG), 0, NG - 1);
    const int bso = b * (NCELL + 1);
    const int bpo = b * N_PTS;

    if (lane < 27) {
        const int cx = cfx + (lane % 3) - 1;
        const int cy = cfy + ((lane / 3) % 3) - 1;
        const int cz = cfz + (lane / 9) - 1;
        if (cx >= 0 && cx < NG && cy >= 0 && cy < NG && cz >= 0 && cz < NG) {
            const int c = cx + NG * (cy + NG * cz);
            const int s = g_binstart[bso + c];
            const int e = g_binstart[bso + c + 1];
            for (int k = s; k < e; ++k) {
                const float4 p = g_cpts[bpo + k];
                const float d2 = fmaf(fm2x, p.x, fmaf(fm2y, p.y, fmaf(fm2z, p.z, p.w)));
                if (d2 < taup) {
                    const int slot = atomicAdd(&bcnt[wv], 1);
                    if (slot < QCAP)
                        buf[wv][slot] = make_float2(d2, __int_as_float(g_cpidx[bpo + k]));
                }
            }
        }
    }
    __syncthreads();

    const int cnt = bcnt[wv];
    const int n = (cnt < QCAP) ? cnt : QCAP;
    for (int i = lane; i < n; i += 64)
        g_qlist[(size_t)g * QCAP + i] = buf[wv][i];
    if (lane == 0) g_qcnt[g * 16] = cnt;   // single producer: plain store
}

// ---------------------------------------------------------------------------
// Loss (verbatim from R21): wave-per-query butterfly top-4 + inline exact
// fallback; per-block slot store; M3/Wx from globals.
// ---------------------------------------------------------------------------
__global__ __launch_bounds__(256) void loss_kernel(
    const float* __restrict__ noisy,
    const float* __restrict__ clean)
{
    __shared__ float red[4];
    const int tid  = threadIdx.x;
    const int wv   = tid >> 6;
    const int lane = tid & 63;
    const int g    = blockIdx.x * 4 + wv;
    const int b    = g >> 12;
    const int p    = (g >> 5) & 127;
    const float* nb = noisy + b * (N_PTS * 3);
    const float* cb = clean + b * (N_PTS * 3);

    const int cnt = g_qcnt[g * 16];
    const int fid = clampi(g_fidx[g], 0, N_PTS - 1);
    const float fx = nb[fid * 3 + 0], fy = nb[fid * 3 + 1], fz = nb[fid * 3 + 2];
    int nn[4];

    if (cnt >= 4 && cnt <= QCAP) {
        const float2* lst = g_qlist + (size_t)g * QCAP;
        unsigned long long e0 = ~0ULL, e1 = ~0ULL;
        if (lane < cnt) {
            const float2 a = lst[lane];
            e0 = packkey(a.x, __float_as_int(a.y));
        }
        if (lane + 64 < cnt) {
            const float2 a = lst[lane + 64];
            e1 = packkey(a.x, __float_as_int(a.y));
        }
        if (e1 < e0) { unsigned long long t = e0; e0 = e1; e1 = t; }

        int c = 0;
#pragma unroll
        for (int r = 0; r < 4; ++r) {
            const unsigned long long h = (c == 0) ? e0 : ((c == 1) ? e1 : ~0ULL);
            unsigned long long m = h;
#pragma unroll
            for (int off = 32; off; off >>= 1) {
                const unsigned long long o = __shfl_xor(m, off);
                if (o < m) m = o;
            }
            if (h == m) c++;
            nn[r] = (int)(m & 0xFFFFFFFFull);
        }
    } else {
        float bd[4]; int bi[4];
#pragma unroll
        for (int t = 0; t < 4; ++t) { bd[t] = BIGF; bi[t] = 0x7fffffff; }
        for (int j = lane; j < N_PTS; j += 64) {
            const float dx = fx - cb[j * 3 + 0];
            const float dy = fy - cb[j * 3 + 1];
            const float dz = fz - cb[j * 3 + 2];
            const float d2 = fmaf(dz, dz, fmaf(dy, dy, dx * dx));
            if (d2 < bd[3]) {
                bd[3] = d2; bi[3] = j;
#pragma unroll
                for (int t = 3; t > 0; --t) {
                    if (bd[t] < bd[t - 1]) {
                        float td = bd[t]; bd[t] = bd[t - 1]; bd[t - 1] = td;
                        int   ti = bi[t]; bi[t] = bi[t - 1]; bi[t - 1] = ti;
                    }
                }
            }
        }
        int cur = 0;
        for (int r = 0; r < 4; ++r) {
            float v  = (cur < 4) ? bd[cur] : BIGF;
            int   vi = (cur < 4) ? bi[cur] : 0x7fffffff;
            int   who = lane;
#pragma unroll
            for (int off = 32; off; off >>= 1) {
                const float v2  = __shfl_down(v, off);
                const int   vi2 = __shfl_down(vi, off);
                const int   w2  = __shfl_down(who, off);
                if (v2 < v || (v2 == v && vi2 < vi)) { v = v2; vi = vi2; who = w2; }
            }
            const int bvi = __shfl(vi, 0);
            const int bwh = __shfl(who, 0);
            nn[r] = bvi;
            if (lane == bwh) cur++;
        }
    }

    float t2 = 0.0f;
    if (lane == 0) {
        const int si = g_sidx[p];
        const float qx = nb[si * 3 + 0], qy = nb[si * 3 + 1], qz = nb[si * 3 + 2];
        const int n0 = clampi(nn[0], 0, N_PTS - 1), n1 = clampi(nn[1], 0, N_PTS - 1);
        const int n2 = clampi(nn[2], 0, N_PTS - 1), n3 = clampi(nn[3], 0, N_PTS - 1);
        const float mx = 0.25f * (cb[n0*3+0] + cb[n1*3+0] + cb[n2*3+0] + cb[n3*3+0]);
        const float my = 0.25f * (cb[n0*3+1] + cb[n1*3+1] + cb[n2*3+1] + cb[n3*3+1]);
        const float mz = 0.25f * (cb[n0*3+2] + cb[n1*3+2] + cb[n2*3+2] + cb[n3*3+2]);

        const float gx = mx - fx, gy = my - fy, gz = mz - fz;
        const float rx = fx - qx, ry = fy - qy, rz = fz - qz;
        const float ex = rx * g_WxS[0] + ry * g_WxS[3] + rz * g_WxS[6] + qx * g_M3[0] + qy * g_M3[3] + qz * g_M3[6];
        const float ey = rx * g_WxS[1] + ry * g_WxS[4] + rz * g_WxS[7] + qx * g_M3[1] + qy * g_M3[4] + qz * g_M3[7];
        const float ez = rx * g_WxS[2] + ry * g_WxS[5] + rz * g_WxS[8] + qx * g_M3[2] + qy * g_M3[5] + qz * g_M3[8];
        const float dx = ex - gx, dy = ey - gy, dz = ez - gz;
        t2 = dx * dx + dy * dy + dz * dz;
        g_qcnt[g * 16] = 0;
    }

    if (lane == 0) red[wv] = t2;
    __syncthreads();
    if (tid == 0) g_lploss[blockIdx.x] = (red[0] + red[1]) + (red[2] + red[3]);
}

// ---------------------------------------------------------------------------
// Final: sum 2048 per-block partials (1 block, 256 thr).
// ---------------------------------------------------------------------------
__global__ __launch_bounds__(256) void final_kernel(float* __restrict__ out)
{
    __shared__ float red[4];
    const int tid = threadIdx.x;
    float v = 0.0f;
    for (int i = tid; i < NLOSSB; i += 256) v += g_lploss[i];
#pragma unroll
    for (int off = 32; off; off >>= 1) v += __shfl_down(v, off);
    if ((tid & 63) == 0) red[tid >> 6] = v;
    __syncthreads();
    if (tid == 0) out[0] = ((red[0] + red[1]) + (red[2] + red[3])) * (50.0f / 8192.0f);
}

extern "C" void kernel_launch(void* const* d_in, const int* in_sizes, int n_in,
                              void* d_out, int out_size, void* d_ws, size_t ws_size,
                              hipStream_t stream)
{
    (void)d_ws; (void)ws_size; (void)in_sizes; (void)n_in; (void)out_size;

    const float* noisy = (const float*)d_in[0];
    const float* clean = (const float*)d_in[1];
    const float* Wf    = (const float*)d_in[3];
    const float* Wx    = (const float*)d_in[4];
    const float* Wc    = (const float*)d_in[5];

    grid_hist_kernel<<<dim3(GB_BLK, N_B), 256, 0, stream>>>(clean);
    grid_scan_kernel<<<N_B, 256, 0, stream>>>(d_in[2], Wf, Wx, Wc);
    grid_scatter_kernel<<<dim3(GB_BLK, N_B), 256, 0, stream>>>(clean);
    knn1_scan_kernel<<<dim3(256, K1SUB), 256, 0, stream>>>(noisy);
    knn1_merge_kernel<<<256, 256, 0, stream>>>(noisy);
    knn2_grid_kernel<<<NLOSSB, 256, 0, stream>>>(noisy);
    loss_kernel<<<NLOSSB, 256, 0, stream>>>(noisy, clean);
    final_kernel<<<1, 256, 0, stream>>>((float*)d_out);
}